// Round 17
// baseline (81.545 us; speedup 1.0000x reference)
//
#include <hip/hip_runtime.h>

// WL-conv factorized:  out[b,c,n,k] = Y0 + e1[c,k]*Y1 + e2[c,k]*Y2 + e3[c,k]*Y3
// with Ym = M^m labels and e_m the elementary symmetric polynomials of
// kernels[c,0..2,k] (per-step operators I + k_t∘M commute).
//
// 4 stream-ordered kernels:
//   prep: labels -> swizzled bf16 Y0                       [R15, unchanged]
//   K1  : fused own-row pack + Y1 = M Y0. NEW: wave-contiguous lig traversal
//         (each wave streams 4 rows x 16 KB contiguously; R16's row-major
//         interleave jumped 16 KB per iteration -> 4.2 TB/s) + depth-4 load
//         pipeline. Coalesced 8KB bits tile store unchanged.
//   K2/K3: 32-row blocks (512 blocks, 2/CU): two 16-row tiles share each
//         B-fragment load; masks+B in depth-4 rolling register pipelines.
//         K3 fuses combine with vectorized float4 epilogue.  [R16, unchanged]
// bits layout: bits[((b*256+rt)*64 + w)*16 + r]  (block-coalesced tiles)
// Y chained in ypos-permuted MFMA-B-fragment layout (coalesced 1KB B loads).
//
// d_out (8 MB): final output only.
// d_ws: bits 8MB | ysw0 | ysw1 | ysw2 (0.5 MB each, swizzled bf16).

#define BB 4
#define NN 4096
#define KK 16
#define CC 8
#define TT 3
#define WPR (NN / 64)
#define YSWZ (KK * NN)   // u16 elements per batch in swizzled Y (65536)

typedef unsigned long long u64;
typedef unsigned int u32;
typedef unsigned short u16;
typedef __attribute__((ext_vector_type(8))) short s16x8;
typedef __attribute__((ext_vector_type(4))) float f32x4v;

__device__ __forceinline__ u32 bf16_rne(float f) {
    u32 u = __float_as_uint(f);
    return (u + 0x7FFFu + ((u >> 16) & 1u)) >> 16;
}
__device__ __forceinline__ float bf16_f32(u32 h) {
    return __uint_as_float(h << 16);
}
__device__ __forceinline__ long ypos(int f, int s) {
    return ((long)(s >> 8) << 12) + (s & 3) * 1024 + ((s >> 7) & 1) * 512 +
           f * 32 + ((s >> 5) & 3) * 8 + ((s >> 2) & 7);
}

// byte (8 mask bits) -> 8 bf16 {0,1} packed in s16x8 (elem i = bit i)
__device__ __forceinline__ s16x8 expand8(u32 byt) {
    u32 n0 = byt & 0xFu, n1 = (byt >> 4) & 0xFu;
    u32 t0 = (n0 * 0x204081u) & 0x01010101u;
    u32 t1 = (n1 * 0x204081u) & 0x01010101u;
    u32 m0 = (t0 << 7) - t0;
    u32 m1 = (t1 << 7) - t1;
    union { u32 w[4]; s16x8 v; } u;
    u.w[0] = __builtin_amdgcn_perm(0u, m0, 0x0C010C00u) << 7;
    u.w[1] = __builtin_amdgcn_perm(0u, m0, 0x0C030C02u) << 7;
    u.w[2] = __builtin_amdgcn_perm(0u, m1, 0x0C010C00u) << 7;
    u.w[3] = __builtin_amdgcn_perm(0u, m1, 0x0C030C02u) << 7;
    return u.v;
}

// ---------------------------------------------------------------- prep ------
__global__ __launch_bounds__(256)
void prep_kernel(const float* __restrict__ labels, u16* __restrict__ ysw0) {
    int gid = blockIdx.x * 256 + threadIdx.x;            // 65536 tasks
    int s4 = (gid & (NN / 4 - 1)) * 4;
    int f  = (gid >> 10) & (KK - 1);
    int b  = gid >> 14;
    long base = (long)b * YSWZ + ypos(f, s4);            // s4 mult of 4: +j*1024
    const float* lp = labels + ((long)b * NN + s4) * KK + f;
#pragma unroll
    for (int j = 0; j < 4; ++j)
        ysw0[base + j * 1024] = (u16)bf16_rne(lp[j * KK]);
}

// ------------------------------------------------------- K1 (pack + spmm) ---
__global__ __launch_bounds__(256, 4)
void spmm1_k(const int* __restrict__ lig, u64* __restrict__ bits,
             const u16* __restrict__ yin, u16* __restrict__ yout)
{
    __shared__ float red[3][4][64];
    __shared__ u64 bl[64][16];                   // masks [word][row] 8KB
    const int bid = blockIdx.x;
    const int rt  = bid & (NN / 16 - 1);
    const int b   = bid >> 8;
    const int tid = threadIdx.x;
    const int lane = tid & 63, ss = tid >> 6;
    const int n16 = lane & 15, g = lane >> 4;
    const int row0 = rt * 16;

    const u16* yb = yin + (long)b * YSWZ + (ss * 16) * 1024 + n16 * 32 + g * 8;
    s16x8 p0[4], p1[4];
#pragma unroll
    for (int i = 0; i < 4; ++i) {
        p0[i] = *(const s16x8*)(yb + i * 1024);
        p1[i] = *(const s16x8*)(yb + i * 1024 + 512);
    }

    {
        // wave ss streams block-rows [4ss, 4ss+4) CONTIGUOUSLY:
        // i = 0..63: row = 4ss + (i>>4), w4 = i&15 (16 consecutive 1KB reqs
        // per row). Ballot/word mapping identical to R16 (only wave->task
        // assignment changed). Depth-4 rolling load pipeline.
        const int* lrow = lig + ((long)b * NN + row0) * NN;
        auto laddr = [&](int i) {
            int row = (ss * 4) + (i >> 4), w4 = i & 15;
            return (const int4*)(lrow + (long)row * NN + w4 * 256 + lane * 4);
        };
        int4 v[4];
#pragma unroll
        for (int i = 0; i < 4; ++i) v[i] = *laddr(i);
#pragma unroll 4
        for (int i = 0; i < 64; ++i) {
            const int slot = i & 3;
            int4 cur = v[slot];
            if (i + 4 < 64) v[slot] = *laddr(i + 4);
            u64 m0 = __ballot(cur.x >= 1);
            u64 m1 = __ballot(cur.y >= 1);
            u64 m2 = __ballot(cur.z >= 1);
            u64 m3 = __ballot(cur.w >= 1);
            if (lane == 0) {
                int row = (ss * 4) + (i >> 4), wq = (i & 15) * 4;
                bl[wq + 0][row] = m0; bl[wq + 1][row] = m1;
                bl[wq + 2][row] = m2; bl[wq + 3][row] = m3;
            }
        }
        __syncthreads();
        uint4* dst = (uint4*)(bits + (long)(b * (NN / 16) + rt) * 1024);
        const uint4* src = (const uint4*)&bl[0][0];
        dst[tid]       = src[tid];
        dst[tid + 256] = src[tid + 256];
    }

    u64 wcs[16];
#pragma unroll
    for (int wi = 0; wi < 16; ++wi) wcs[wi] = bl[ss * 16 + wi][n16];

    f32x4v accA = {0.f, 0.f, 0.f, 0.f}, accB = {0.f, 0.f, 0.f, 0.f};
#pragma unroll
    for (int wi = 0; wi < 16; ++wi) {
        const int slot = wi & 3;
        s16x8 b0 = p0[slot], b1 = p1[slot];
        if (wi + 4 < 16) {
            p0[slot] = *(const s16x8*)(yb + (wi + 4) * 1024);
            p1[slot] = *(const s16x8*)(yb + (wi + 4) * 1024 + 512);
        }
        u64 h = wcs[wi] >> (g * 8);
        accA = __builtin_amdgcn_mfma_f32_16x16x32_bf16(expand8((u32)h & 0xFFu), b0, accA, 0, 0, 0);
        accB = __builtin_amdgcn_mfma_f32_16x16x32_bf16(expand8(((u32)(h >> 32)) & 0xFFu), b1, accB, 0, 0, 0);
    }

    f32x4v acc;
#pragma unroll
    for (int r = 0; r < 4; ++r) acc[r] = accA[r] + accB[r];

    if (ss != 0) {
#pragma unroll
        for (int r = 0; r < 4; ++r) red[ss - 1][r][lane] = acc[r];
    }
    __syncthreads();
    if (ss == 0) {
#pragma unroll
        for (int r = 0; r < 4; ++r)
            acc[r] += red[0][r][lane] + red[1][r][lane] + red[2][r][lane];
        const int s0 = row0 + 4 * g;
        const long ybase = (long)b * YSWZ + ypos(n16, s0);
#pragma unroll
        for (int r = 0; r < 4; ++r)
            yout[ybase + r * 1024] = (u16)bf16_rne(acc[r]);
    }
}

// --------------------------------------------- K2/K3: 32-row blocks ---------
template<bool LAST>
__global__ __launch_bounds__(256, 2)
void spmm2_k(const u64* __restrict__ bits, const u16* __restrict__ yin,
             u16* __restrict__ yout, const u16* __restrict__ ysw1,
             const u16* __restrict__ ysw2, const float* __restrict__ labels,
             const float* __restrict__ ker, float* __restrict__ out)
{
    __shared__ float red[2][3][4][64];                    // 6 KB
    __shared__ float t1[32][16], t2[32][16], t3[32][16];  // 6 KB (LAST)
    const int bid = blockIdx.x;
    const int rtp = bid & (NN / 32 - 1);
    const int b   = bid >> 7;
    const int tid = threadIdx.x;
    const int lane = tid & 63, ss = tid >> 6;
    const int n16 = lane & 15, g = lane >> 4;
    const int row0 = rtp * 32;
    const int rt0 = 2 * rtp, rt1 = 2 * rtp + 1;

    const u64* bb0 = bits + ((long)(b * (NN / 16) + rt0) * 64 + ss * 16) * 16 + n16;
    const u64* bb1 = bits + ((long)(b * (NN / 16) + rt1) * 64 + ss * 16) * 16 + n16;
    const u16* yb  = yin + (long)b * YSWZ + (ss * 16) * 1024 + n16 * 32 + g * 8;

    s16x8 p0[4], p1[4]; u64 m0[4], m1[4];
#pragma unroll
    for (int i = 0; i < 4; ++i) {
        p0[i] = *(const s16x8*)(yb + i * 1024);
        p1[i] = *(const s16x8*)(yb + i * 1024 + 512);
        m0[i] = bb0[i * 16];
        m1[i] = bb1[i * 16];
    }

    f32x4v accA0 = {0.f,0.f,0.f,0.f}, accB0 = {0.f,0.f,0.f,0.f};
    f32x4v accA1 = {0.f,0.f,0.f,0.f}, accB1 = {0.f,0.f,0.f,0.f};
#pragma unroll
    for (int wi = 0; wi < 16; ++wi) {
        const int slot = wi & 3;
        s16x8 b0 = p0[slot], b1 = p1[slot];
        u64 h0 = m0[slot], h1 = m1[slot];
        if (wi + 4 < 16) {
            p0[slot] = *(const s16x8*)(yb + (wi + 4) * 1024);
            p1[slot] = *(const s16x8*)(yb + (wi + 4) * 1024 + 512);
            m0[slot] = bb0[(wi + 4) * 16];
            m1[slot] = bb1[(wi + 4) * 16];
        }
        u64 ha = h0 >> (g * 8), hb = h1 >> (g * 8);
        accA0 = __builtin_amdgcn_mfma_f32_16x16x32_bf16(expand8((u32)ha & 0xFFu), b0, accA0, 0, 0, 0);
        accB0 = __builtin_amdgcn_mfma_f32_16x16x32_bf16(expand8(((u32)(ha >> 32)) & 0xFFu), b1, accB0, 0, 0, 0);
        accA1 = __builtin_amdgcn_mfma_f32_16x16x32_bf16(expand8((u32)hb & 0xFFu), b0, accA1, 0, 0, 0);
        accB1 = __builtin_amdgcn_mfma_f32_16x16x32_bf16(expand8(((u32)(hb >> 32)) & 0xFFu), b1, accB1, 0, 0, 0);
    }

    f32x4v acc0, acc1;
#pragma unroll
    for (int r = 0; r < 4; ++r) { acc0[r] = accA0[r] + accB0[r];
                                  acc1[r] = accA1[r] + accB1[r]; }

    const int s0a = row0 + 4 * g;
    const int s0b = row0 + 16 + 4 * g;
    const long yba = (long)b * YSWZ + ypos(n16, s0a);
    const long ybb = (long)b * YSWZ + ypos(n16, s0b);
    float y1a[4], y2a[4], y1b[4], y2b[4];
    if (LAST && ss == 0) {
#pragma unroll
        for (int r = 0; r < 4; ++r) {
            y1a[r] = bf16_f32(ysw1[yba + r * 1024]);
            y2a[r] = bf16_f32(ysw2[yba + r * 1024]);
            y1b[r] = bf16_f32(ysw1[ybb + r * 1024]);
            y2b[r] = bf16_f32(ysw2[ybb + r * 1024]);
        }
    }

    if (ss != 0) {
#pragma unroll
        for (int r = 0; r < 4; ++r) {
            red[0][ss - 1][r][lane] = acc0[r];
            red[1][ss - 1][r][lane] = acc1[r];
        }
    }
    __syncthreads();
    if (ss == 0) {
#pragma unroll
        for (int r = 0; r < 4; ++r) {
            acc0[r] += red[0][0][r][lane] + red[0][1][r][lane] + red[0][2][r][lane];
            acc1[r] += red[1][0][r][lane] + red[1][1][r][lane] + red[1][2][r][lane];
        }
        if (!LAST) {
#pragma unroll
            for (int r = 0; r < 4; ++r) {
                yout[yba + r * 1024] = (u16)bf16_rne(acc0[r]);
                yout[ybb + r * 1024] = (u16)bf16_rne(acc1[r]);
            }
        } else {
#pragma unroll
            for (int r = 0; r < 4; ++r) {
                t1[4 * g + r][n16]      = y1a[r];
                t2[4 * g + r][n16]      = y2a[r];
                t3[4 * g + r][n16]      = acc0[r];
                t1[16 + 4 * g + r][n16] = y1b[r];
                t2[16 + 4 * g + r][n16] = y2b[r];
                t3[16 + 4 * g + r][n16] = acc1[r];
            }
        }
    }

    if (LAST) {
        __syncthreads();
#pragma unroll
        for (int j = 0; j < 4; ++j) {
            int fi = tid + j * 256;
            int c = fi >> 7, row = (fi >> 2) & 31, k4 = fi & 3;
            const float4* kf = (const float4*)ker;
            float4 a = kf[(c * TT + 0) * 4 + k4];
            float4 d = kf[(c * TT + 1) * 4 + k4];
            float4 e = kf[(c * TT + 2) * 4 + k4];
            float4 e1, e2, e3;
            e1.x = a.x + d.x + e.x;               e1.y = a.y + d.y + e.y;
            e1.z = a.z + d.z + e.z;               e1.w = a.w + d.w + e.w;
            e2.x = a.x*d.x + a.x*e.x + d.x*e.x;   e2.y = a.y*d.y + a.y*e.y + d.y*e.y;
            e2.z = a.z*d.z + a.z*e.z + d.z*e.z;   e2.w = a.w*d.w + a.w*e.w + d.w*e.w;
            e3.x = a.x * d.x * e.x;               e3.y = a.y * d.y * e.y;
            e3.z = a.z * d.z * e.z;               e3.w = a.w * d.w * e.w;
            float4 y0 = *(const float4*)(labels + ((long)b * NN + row0 + row) * KK + k4 * 4);
            float4 v1 = *(const float4*)&t1[row][k4 * 4];
            float4 v2 = *(const float4*)&t2[row][k4 * 4];
            float4 v3 = *(const float4*)&t3[row][k4 * 4];
            float4 r;
            r.x = y0.x + e1.x * v1.x + e2.x * v2.x + e3.x * v3.x;
            r.y = y0.y + e1.y * v1.y + e2.y * v2.y + e3.y * v3.y;
            r.z = y0.z + e1.z * v1.z + e2.z * v2.z + e3.z * v3.z;
            r.w = y0.w + e1.w * v1.w + e2.w * v2.w + e3.w * v3.w;
            *(float4*)(out + (((long)b * CC + c) * NN + row0 + row) * KK + k4 * 4) = r;
        }
    }
}

// --------------------------------------------------------------- launch -----
extern "C" void kernel_launch(void* const* d_in, const int* in_sizes, int n_in,
                              void* d_out, int out_size, void* d_ws, size_t ws_size,
                              hipStream_t stream) {
    const float* labels = (const float*)d_in[0];   // [B,N,K] f32
    const int*   lig    = (const int*)d_in[1];     // [B,N,N] i32
    const float* ker    = (const float*)d_in[2];   // [C,T,K] f32
    float* out = (float*)d_out;

    u64* bits = (u64*)d_ws;                        // 8 MB
    u16* ysw0 = (u16*)((char*)d_ws + (long)BB * WPR * NN * 8);
    u16* ysw1 = ysw0 + (long)BB * YSWZ;
    u16* ysw2 = ysw1 + (long)BB * YSWZ;

    hipLaunchKernelGGL(prep_kernel, dim3(256), dim3(256), 0, stream,
                       labels, ysw0);

    hipLaunchKernelGGL(spmm1_k, dim3(BB * (NN / 16)), dim3(256), 0, stream,
                       lig, bits, ysw0, ysw1);
    hipLaunchKernelGGL((spmm2_k<false>), dim3(BB * (NN / 32)), dim3(256), 0,
                       stream, bits, ysw1, ysw2, (const u16*)nullptr,
                       (const u16*)nullptr, (const float*)nullptr,
                       (const float*)nullptr, (float*)nullptr);
    hipLaunchKernelGGL((spmm2_k<true>),  dim3(BB * (NN / 32)), dim3(256), 0,
                       stream, bits, ysw2, (u16*)nullptr, ysw1, ysw2,
                       labels, ker, out);
}